// Round 10
// baseline (7204.749 us; speedup 1.0000x reference)
//
#include <hip/hip_runtime.h>
#include <hip/hip_bf16.h>

#define H 2048
#define T 2048
#define INPUT 1024
#define FOURH 8192
#define NBLK 256
#define RING 512  // ring slots; epoch barrier every 256 steps bounds skew < 512

typedef __attribute__((ext_vector_type(8))) short bf16x8;
typedef __attribute__((ext_vector_type(4))) float f32x4_t;

__device__ __forceinline__ unsigned short f2bf(float f) {
  union { float f; unsigned u; } v; v.f = f;
  unsigned r = v.u + 0x7FFFu + ((v.u >> 16) & 1u);
  return (unsigned short)(r >> 16);
}

// tanh via single exp: tanh(x) = (1-e^{-2x})/(1+e^{-2x}); clamp avoids inf-inf NaN
__device__ __forceinline__ float fast_tanh(float x) {
  float e = __expf(fminf(-2.f * x, 80.f));
  return (1.f - e) / (1.f + e);
}

// ---------------- prep: bf16 conversions + dt_prev table + flag init ----------------
__global__ void prep_kernel(const float* __restrict__ x, const float* __restrict__ W_ih,
                            const float* __restrict__ time_, short* __restrict__ xb,
                            short* __restrict__ wb, float* __restrict__ dtp,
                            unsigned* __restrict__ flags) {
  size_t i = (size_t)blockIdx.x * blockDim.x + threadIdx.x;
  size_t stride = (size_t)gridDim.x * blockDim.x;
  if (i < (size_t)T * INPUT) xb[i] = (short)f2bf(x[i]);
  for (size_t j = i; j < (size_t)FOURH * INPUT; j += stride) wb[j] = (short)f2bf(W_ih[j]);
  if (i < T) dtp[i] = (i >= 2) ? (time_[i - 1] - time_[i - 2]) : 0.0f;
  if (i < NBLK) flags[i] = 0u;
}

// ---------------- xg GEMM (R17): 8x m-reuse per B-fragment, verified -150us ----------
__global__ void __launch_bounds__(256)
gemm_xg(const short* __restrict__ A, const short* __restrict__ B,
        const float* __restrict__ b_ih, const float* __restrict__ b_hh,
        float* __restrict__ xg) {
  int wave = threadIdx.x >> 6;
  int lane = threadIdx.x & 63;
  int bid = blockIdx.x;
  int m0 = (bid & 15) << 7;                   // 16 m-supertiles of 128 rows
  int n0 = ((bid >> 4) << 6) + (wave << 4);   // 128 n-panels of 64
  int r16 = lane & 15, q = lane >> 4;
  const short* ap = A + (size_t)(m0 + r16) * INPUT + q * 8;
  const short* bp = B + (size_t)(n0 + r16) * INPUT + q * 8;
  f32x4_t acc[8];
#pragma unroll
  for (int s = 0; s < 8; ++s) acc[s] = {0.f, 0.f, 0.f, 0.f};
  for (int k = 0; k < INPUT; k += 32) {
    bf16x8 bv = *(const bf16x8*)(bp + k);
#pragma unroll
    for (int s = 0; s < 8; ++s) {
      bf16x8 av = *(const bf16x8*)(ap + (size_t)(s << 4) * INPUT + k);
      acc[s] = __builtin_amdgcn_mfma_f32_16x16x32_bf16(av, bv, acc[s], 0, 0, 0);
    }
  }
  int n = n0 + r16;
  float bias = b_ih[n] + b_hh[n];
#pragma unroll
  for (int s = 0; s < 8; ++s) {
#pragma unroll
    for (int r = 0; r < 4; ++r) {
      int m = m0 + (s << 4) + q * 4 + r;
      xg[(size_t)m * FOURH + n] = acc[s][r] + bias;
    }
  }
}

// ---------------- grid barrier (epochs: 1..7 ring WAR, 8 post-loop, 9 post-attn) ------
__device__ __forceinline__ void epoch_bar(unsigned* flags, unsigned e) {
  __syncthreads();
  if (threadIdx.x == 0)
    __hip_atomic_store(&flags[blockIdx.x], e, __ATOMIC_RELEASE, __HIP_MEMORY_SCOPE_AGENT);
  if (threadIdx.x < NBLK) {
    while (__hip_atomic_load(&flags[threadIdx.x], __ATOMIC_RELAXED,
                             __HIP_MEMORY_SCOPE_AGENT) < e) {
    }
  }
  __builtin_amdgcn_fence(__ATOMIC_ACQUIRE, "agent");
  __syncthreads();
}

// ---------------- persistent recurrence: tagged 8B dataflow + fused attention tail ----
// Core = R11 verified local optimum (six protocol variants regressed: R9 predication
// +8%, R10 barrier removal +112%, R14 relay +69%, R15 sleep +23%, R16 coalesced
// publish +9%, R11 early-publish +-0). R18 changes:
//  (a) 2-DEEP PIPELINED POLL: two batched unconditional 4x8B loads in flight,
//      check older while younger flies -> sampling period ~L/2 instead of L.
//      sched_barrier(0) pins issue-before-check (R9 lesson: compiler serializes).
//      Batches stay unconditional+batched; BOTH barriers stay. Flood 2x is
//      non-binding per R15/R16.
//  (b) FUSED ATTENTION TAIL: epoch_bar(8) -> per-wave attn dot (t = u), bar(9) ->
//      blocks<64 do redundant softmax + 32-row ctx chunks + atomicAdd. Removes 3
//      kernel launches and two 16MB re-read dispatches.
__global__ void __launch_bounds__(512, 2)
lstm_rec(const float* __restrict__ xg, const float* __restrict__ W_hh,
         const float* __restrict__ decay_w, const float* __restrict__ decay_b,
         const float* __restrict__ h0, const float* __restrict__ c0,
         const float* __restrict__ dtp, float* __restrict__ hs,
         unsigned long long* ring, unsigned* flags, float* __restrict__ attn,
         float* __restrict__ out) {
  const int wave = threadIdx.x >> 6;
  const int lane = threadIdx.x & 63;
  const int u = (blockIdx.x << 3) + wave;
  __shared__ __align__(16) float lh[H];
  __shared__ float red[16];

  // weights: wreg[g][4p+e] = W_hh[g*H+u][256p + 4*lane + e]  (coalesced b128 loads)
  float wreg[4][32];
#pragma unroll
  for (int g = 0; g < 4; ++g) {
    const float* wr = W_hh + (size_t)(g * H + u) * H + (lane << 2);
#pragma unroll
    for (int p = 0; p < 8; ++p)
      *(f32x4_t*)&wreg[g][p << 2] = *(const f32x4_t*)(wr + (p << 8));
  }
  const float dw = decay_w[u], db = decay_b[u];
  float c = c0[u];  // uniform across all lanes (redundant compute, no divergence)
  if (lane == 0) {
    union { float f; unsigned u; } hv; hv.f = h0[u];  // gamma[0] = 1, tag = 1
    __hip_atomic_store(&ring[u], (1ull << 32) | hv.u, __ATOMIC_RELAXED,
                       __HIP_MEMORY_SCOPE_AGENT);
  }

#define PISSUE(d0, d1, d2, d3)                                                         \
  d0 = __hip_atomic_load(sp,       __ATOMIC_RELAXED, __HIP_MEMORY_SCOPE_AGENT);        \
  d1 = __hip_atomic_load(sp + 64,  __ATOMIC_RELAXED, __HIP_MEMORY_SCOPE_AGENT);        \
  d2 = __hip_atomic_load(sp + 128, __ATOMIC_RELAXED, __HIP_MEMORY_SCOPE_AGENT);        \
  d3 = __hip_atomic_load(sp + 192, __ATOMIC_RELAXED, __HIP_MEMORY_SCOPE_AGENT);
#define PTAGOK(d0, d1, d2, d3)                                                         \
  (((unsigned)(d0 >> 32) == want) & ((unsigned)(d1 >> 32) == want) &                   \
   ((unsigned)(d2 >> 32) == want) & ((unsigned)(d3 >> 32) == want))

  for (int t = 0; t < T; ++t) {
    if ((t & 255) == 0 && t) epoch_bar(flags, (unsigned)(t >> 8));

    // off-critical-path prefetch: lane e<4 loads gate-e input; lane 0 next gamma
    float xv = 0.f, gam = 0.f;
    if (lane < 4) xv = xg[(size_t)t * FOURH + (size_t)lane * H + u];
    if (lane == 0 && t + 1 < T) gam = __expf(-fmaxf(0.f, dtp[t + 1] * dw + db));

    // 2-deep pipelined poll: two unconditional batches in flight, check the older
    const unsigned want = (unsigned)t + 1u;
    unsigned long long* sp =
        ring + (((size_t)(t & (RING - 1)) << 11) | (unsigned)((wave << 8) + lane));
    unsigned long long w0, w1, w2, w3, v0, v1, v2, v3;
    PISSUE(w0, w1, w2, w3)
    for (;;) {
      PISSUE(v0, v1, v2, v3)
      __builtin_amdgcn_sched_barrier(0);
      if (__all(PTAGOK(w0, w1, w2, w3))) break;
      PISSUE(w0, w1, w2, w3)
      __builtin_amdgcn_sched_barrier(0);
      if (__all(PTAGOK(v0, v1, v2, v3))) { w0 = v0; w1 = v1; w2 = v2; w3 = v3; break; }
    }
    // dedup through LDS, identity layout lh[i] = h_i
    {
      float* lw = lh + (wave << 8) + lane;
      union { unsigned u; float f; } v;
      v.u = (unsigned)w0; lw[0]   = v.f;
      v.u = (unsigned)w1; lw[64]  = v.f;
      v.u = (unsigned)w2; lw[128] = v.f;
      v.u = (unsigned)w3; lw[192] = v.f;
    }
    __syncthreads();

    float a0 = 0.f, a1 = 0.f, a2 = 0.f, a3 = 0.f;
#pragma unroll
    for (int p = 0; p < 8; ++p) {
      f32x4_t h4 = *(const f32x4_t*)(lh + (p << 8) + (lane << 2));  // conflict-free b128
#pragma unroll
      for (int e = 0; e < 4; ++e) {
        float h = h4[e];
        a0 += wreg[0][(p << 2) + e] * h;
        a1 += wreg[1][(p << 2) + e] * h;
        a2 += wreg[2][(p << 2) + e] * h;
        a3 += wreg[3][(p << 2) + e] * h;
      }
    }
#pragma unroll
    for (int s = 32; s >= 1; s >>= 1) {
      a0 += __shfl_xor(a0, s);
      a1 += __shfl_xor(a1, s);
      a2 += __shfl_xor(a2, s);
      a3 += __shfl_xor(a3, s);
    }

    // activations parallelized: lane e<4 does one transcendental (sigma form:
    // tanh(x) = 2*sigma(2x)-1), 4 shfl broadcasts, then uniform c/h on all lanes.
    {
      float pre = ((lane == 0) ? a0 : (lane == 1) ? a1 : (lane == 2) ? a2 : a3) + xv;
      float ps = (lane == 2) ? 2.f * pre : pre;
      float sg = 1.f / (1.f + __expf(-ps));
      float act = (lane == 2) ? 2.f * sg - 1.f : sg;
      float iv = __shfl(act, 0), fv = __shfl(act, 1), gv = __shfl(act, 2),
            ov = __shfl(act, 3);
      c = fv * c + iv * gv;
      float h = ov * fast_tanh(c);
      if (lane == 0 && t + 1 < T) {  // publish: the chip-wide critical path
        union { float f; unsigned u; } hv; hv.f = h * gam;
        size_t slot = (size_t)((t + 1) & (RING - 1)) << 11;
        __hip_atomic_store(&ring[slot | (unsigned)u],
                           (((unsigned long long)(t + 2)) << 32) | hv.u,
                           __ATOMIC_RELAXED, __HIP_MEMORY_SCOPE_AGENT);
      }
      if (lane == 1) hs[(size_t)t * H + u] = h;  // pristine fp32 h for attention
    }
    __syncthreads();  // keep publish ahead of next step's poll flood (see R7)
  }
#undef PISSUE
#undef PTAGOK

  // ================= fused attention tail =================
  epoch_bar(flags, 8);  // all hs[t][*] visible chip-wide

  // attn[t] = dot(hs[t], hs[T-1]); wave handles t == u (256 blocks x 8 waves = 2048)
  {
    const float* rowp = hs + (size_t)u * H;
    const float* hfp = hs + (size_t)(T - 1) * H;
    float s = 0.f;
#pragma unroll
    for (int p = 0; p < 8; ++p) {
      f32x4_t rv = *(const f32x4_t*)(rowp + (p << 8) + (lane << 2));
      f32x4_t fv = *(const f32x4_t*)(hfp + (p << 8) + (lane << 2));
      s += rv[0] * fv[0] + rv[1] * fv[1] + rv[2] * fv[2] + rv[3] * fv[3];
    }
#pragma unroll
    for (int o = 32; o; o >>= 1) s += __shfl_xor(s, o);
    if (lane == 0) attn[u] = s;
  }
  epoch_bar(flags, 9);  // attn[] visible

  if (blockIdx.x >= 64) return;

  // redundant softmax (identical per block) -> weights in lh[]; then 32-row ctx chunk
  {
    const int tid = threadIdx.x;
    f32x4_t av = *(const f32x4_t*)(attn + (tid << 2));
    float m = fmaxf(fmaxf(av[0], av[1]), fmaxf(av[2], av[3]));
#pragma unroll
    for (int o = 32; o; o >>= 1) m = fmaxf(m, __shfl_xor(m, o));
    if (lane == 0) red[wave] = m;
    __syncthreads();
    float M = red[0];
#pragma unroll
    for (int i = 1; i < 8; ++i) M = fmaxf(M, red[i]);
    float e0 = __expf(av[0] - M), e1 = __expf(av[1] - M), e2 = __expf(av[2] - M),
          e3 = __expf(av[3] - M);
    float s = e0 + e1 + e2 + e3;
#pragma unroll
    for (int o = 32; o; o >>= 1) s += __shfl_xor(s, o);
    __syncthreads();  // red[] reuse WAR
    if (lane == 0) red[wave] = s;
    __syncthreads();
    float S = red[0] + red[1] + red[2] + red[3] + red[4] + red[5] + red[6] + red[7];
    float inv = 1.f / S;
    f32x4_t wv = {e0 * inv, e1 * inv, e2 * inv, e3 * inv};
    *(f32x4_t*)(lh + (tid << 2)) = wv;
    __syncthreads();

    // ctx: this block accumulates t-range [32*bid, 32*bid+32) into out[0..2047]
    const int tB = blockIdx.x << 5;
    const float* hp = hs + (size_t)tB * H + (tid << 2);
    float ac0 = 0.f, ac1 = 0.f, ac2 = 0.f, ac3 = 0.f;
#pragma unroll 4
    for (int tt = 0; tt < 32; ++tt) {
      float wt = lh[tB + tt];  // LDS broadcast
      f32x4_t hv = *(const f32x4_t*)hp;
      hp += H;
      ac0 += wt * hv[0]; ac1 += wt * hv[1]; ac2 += wt * hv[2]; ac3 += wt * hv[3];
    }
    int hbase = tid << 2;
    atomicAdd(&out[hbase + 0], ac0);
    atomicAdd(&out[hbase + 1], ac1);
    atomicAdd(&out[hbase + 2], ac2);
    atomicAdd(&out[hbase + 3], ac3);
  }
}

// ---------------- launch ----------------
extern "C" void kernel_launch(void* const* d_in, const int* in_sizes, int n_in,
                              void* d_out, int out_size, void* d_ws, size_t ws_size,
                              hipStream_t stream) {
  const float* x       = (const float*)d_in[0];
  const float* time_   = (const float*)d_in[1];
  const float* W_ih    = (const float*)d_in[2];
  const float* W_hh    = (const float*)d_in[3];
  const float* b_ih    = (const float*)d_in[4];
  const float* b_hh    = (const float*)d_in[5];
  const float* decay_w = (const float*)d_in[6];
  const float* decay_b = (const float*)d_in[7];
  const float* h0      = (const float*)d_in[8];
  const float* c0      = (const float*)d_in[9];

  char* ws = (char*)d_ws;
  float*    xg   = (float*)ws;                          // 64 MB  [T][4H]
  float*    hs   = (float*)(ws + (64u << 20));          // 16 MB  [T][H]
  short*    xb   = (short*)(ws + (80u << 20));          // 4 MB
  short*    wb   = (short*)(ws + (84u << 20));          // 16 MB
  unsigned long long* ring = (unsigned long long*)(ws + (100u << 20)); // 8 MB [RING][H]
  float*    dtp  = (float*)(ws + (108u << 20));
  float*    attn = dtp + T;
  unsigned* flags = (unsigned*)(attn + T);
  float*    outp = (float*)d_out;

  prep_kernel<<<8192, 256, 0, stream>>>(x, W_ih, time_, xb, wb, dtp, flags);

  gemm_xg<<<2048, 256, 0, stream>>>(xb, wb, b_ih, b_hh, xg);

  (void)hipMemsetAsync(d_out, 0, out_size * sizeof(float), stream);

  {
    void* args[] = {&xg, (void*)&W_hh, (void*)&decay_w, (void*)&decay_b,
                    (void*)&h0, (void*)&c0, &dtp, &hs, &ring, &flags, &attn, &outp};
    (void)hipLaunchCooperativeKernel((void*)lstm_rec, dim3(NBLK), dim3(512), args, 0, stream);
  }
}

// Round 11
// 6206.140 us; speedup vs baseline: 1.1609x; 1.1609x over previous
//
#include <hip/hip_runtime.h>
#include <hip/hip_bf16.h>

#define H 2048
#define T 2048
#define INPUT 1024
#define FOURH 8192
#define NBLK 256
#define RING 512  // ring slots; epoch barrier every 256 steps bounds skew < 512

typedef __attribute__((ext_vector_type(8))) short bf16x8;
typedef __attribute__((ext_vector_type(4))) float f32x4_t;

__device__ __forceinline__ unsigned short f2bf(float f) {
  union { float f; unsigned u; } v; v.f = f;
  unsigned r = v.u + 0x7FFFu + ((v.u >> 16) & 1u);
  return (unsigned short)(r >> 16);
}

// tanh via single exp: tanh(x) = (1-e^{-2x})/(1+e^{-2x}); clamp avoids inf-inf NaN
__device__ __forceinline__ float fast_tanh(float x) {
  float e = __expf(fminf(-2.f * x, 80.f));
  return (1.f - e) / (1.f + e);
}

// ---------------- prep: bf16 conversions + dt_prev table + flag init ----------------
__global__ void prep_kernel(const float* __restrict__ x, const float* __restrict__ W_ih,
                            const float* __restrict__ time_, short* __restrict__ xb,
                            short* __restrict__ wb, float* __restrict__ dtp,
                            unsigned* __restrict__ flags) {
  size_t i = (size_t)blockIdx.x * blockDim.x + threadIdx.x;
  size_t stride = (size_t)gridDim.x * blockDim.x;
  if (i < (size_t)T * INPUT) xb[i] = (short)f2bf(x[i]);
  for (size_t j = i; j < (size_t)FOURH * INPUT; j += stride) wb[j] = (short)f2bf(W_ih[j]);
  if (i < T) dtp[i] = (i >= 2) ? (time_[i - 1] - time_[i - 2]) : 0.0f;
  if (i < NBLK) flags[i] = 0u;
}

// ---------------- xg GEMM (R17): 8x m-reuse per B-fragment, verified -150us ----------
__global__ void __launch_bounds__(256)
gemm_xg(const short* __restrict__ A, const short* __restrict__ B,
        const float* __restrict__ b_ih, const float* __restrict__ b_hh,
        float* __restrict__ xg) {
  int wave = threadIdx.x >> 6;
  int lane = threadIdx.x & 63;
  int bid = blockIdx.x;
  int m0 = (bid & 15) << 7;                   // 16 m-supertiles of 128 rows
  int n0 = ((bid >> 4) << 6) + (wave << 4);   // 128 n-panels of 64
  int r16 = lane & 15, q = lane >> 4;
  const short* ap = A + (size_t)(m0 + r16) * INPUT + q * 8;
  const short* bp = B + (size_t)(n0 + r16) * INPUT + q * 8;
  f32x4_t acc[8];
#pragma unroll
  for (int s = 0; s < 8; ++s) acc[s] = {0.f, 0.f, 0.f, 0.f};
  for (int k = 0; k < INPUT; k += 32) {
    bf16x8 bv = *(const bf16x8*)(bp + k);
#pragma unroll
    for (int s = 0; s < 8; ++s) {
      bf16x8 av = *(const bf16x8*)(ap + (size_t)(s << 4) * INPUT + k);
      acc[s] = __builtin_amdgcn_mfma_f32_16x16x32_bf16(av, bv, acc[s], 0, 0, 0);
    }
  }
  int n = n0 + r16;
  float bias = b_ih[n] + b_hh[n];
#pragma unroll
  for (int s = 0; s < 8; ++s) {
#pragma unroll
    for (int r = 0; r < 4; ++r) {
      int m = m0 + (s << 4) + q * 4 + r;
      xg[(size_t)m * FOURH + n] = acc[s][r] + bias;
    }
  }
}

// ---------------- grid barrier (epochs: 1..7 ring WAR, 8 post-loop, 9 post-attn) ------
__device__ __forceinline__ void epoch_bar(unsigned* flags, unsigned e) {
  __syncthreads();
  if (threadIdx.x == 0)
    __hip_atomic_store(&flags[blockIdx.x], e, __ATOMIC_RELEASE, __HIP_MEMORY_SCOPE_AGENT);
  if (threadIdx.x < NBLK) {
    while (__hip_atomic_load(&flags[threadIdx.x], __ATOMIC_RELAXED,
                             __HIP_MEMORY_SCOPE_AGENT) < e) {
    }
  }
  __builtin_amdgcn_fence(__ATOMIC_ACQUIRE, "agent");
  __syncthreads();
}

// ---------------- persistent recurrence: tagged 8B dataflow + fused attention tail ----
// Core = EXACT R11 (verified local optimum). SEVEN protocol variants regressed:
//   R9 predication +8% | R10 barrier removal +112% | R14 relay +69% | R15 sleep +23%
//   R16 coalesced publish +9% | R18 2-deep pipelined poll +16% | R11 early-pub +-0
// The spin protocol is FINAL: single batched unconditional 4x8B poll, tight loop,
// both per-step barriers. Step period = IF round-trip x ~2-3 rounds + compute.
// R19 = R11 core + R18's fused attention tail (verified -90us vs separate kernels).
__global__ void __launch_bounds__(512, 2)
lstm_rec(const float* __restrict__ xg, const float* __restrict__ W_hh,
         const float* __restrict__ decay_w, const float* __restrict__ decay_b,
         const float* __restrict__ h0, const float* __restrict__ c0,
         const float* __restrict__ dtp, float* __restrict__ hs,
         unsigned long long* ring, unsigned* flags, float* __restrict__ attn,
         float* __restrict__ out) {
  const int wave = threadIdx.x >> 6;
  const int lane = threadIdx.x & 63;
  const int u = (blockIdx.x << 3) + wave;
  __shared__ __align__(16) float lh[H];
  __shared__ float red[16];

  // weights: wreg[g][4p+e] = W_hh[g*H+u][256p + 4*lane + e]  (coalesced b128 loads)
  float wreg[4][32];
#pragma unroll
  for (int g = 0; g < 4; ++g) {
    const float* wr = W_hh + (size_t)(g * H + u) * H + (lane << 2);
#pragma unroll
    for (int p = 0; p < 8; ++p)
      *(f32x4_t*)&wreg[g][p << 2] = *(const f32x4_t*)(wr + (p << 8));
  }
  const float dw = decay_w[u], db = decay_b[u];
  float c = c0[u];  // uniform across all lanes (redundant compute, no divergence)
  if (lane == 0) {
    union { float f; unsigned u; } hv; hv.f = h0[u];  // gamma[0] = 1, tag = 1
    __hip_atomic_store(&ring[u], (1ull << 32) | hv.u, __ATOMIC_RELAXED,
                       __HIP_MEMORY_SCOPE_AGENT);
  }

  for (int t = 0; t < T; ++t) {
    if ((t & 255) == 0 && t) epoch_bar(flags, (unsigned)(t >> 8));

    // off-critical-path prefetch: lane e<4 loads gate-e input; lane 0 next gamma
    float xv = 0.f, gam = 0.f;
    if (lane < 4) xv = xg[(size_t)t * FOURH + (size_t)lane * H + u];
    if (lane == 0 && t + 1 < T) gam = __expf(-fmaxf(0.f, dtp[t + 1] * dw + db));

    // coalesced TIGHT poll of this wave's 1/8 slice (4 x 8B per lane, lane-contiguous)
    const unsigned want = (unsigned)t + 1u;
    unsigned long long* sp =
        ring + (((size_t)(t & (RING - 1)) << 11) | (unsigned)((wave << 8) + lane));
    unsigned long long w0, w1, w2, w3;
    for (;;) {
      w0 = __hip_atomic_load(sp,       __ATOMIC_RELAXED, __HIP_MEMORY_SCOPE_AGENT);
      w1 = __hip_atomic_load(sp + 64,  __ATOMIC_RELAXED, __HIP_MEMORY_SCOPE_AGENT);
      w2 = __hip_atomic_load(sp + 128, __ATOMIC_RELAXED, __HIP_MEMORY_SCOPE_AGENT);
      w3 = __hip_atomic_load(sp + 192, __ATOMIC_RELAXED, __HIP_MEMORY_SCOPE_AGENT);
      int bad = ((unsigned)(w0 >> 32) != want) | ((unsigned)(w1 >> 32) != want) |
                ((unsigned)(w2 >> 32) != want) | ((unsigned)(w3 >> 32) != want);
      if (!__any(bad)) break;
    }
    // dedup through LDS, identity layout lh[i] = h_i
    {
      float* lw = lh + (wave << 8) + lane;
      union { unsigned u; float f; } v;
      v.u = (unsigned)w0; lw[0]   = v.f;
      v.u = (unsigned)w1; lw[64]  = v.f;
      v.u = (unsigned)w2; lw[128] = v.f;
      v.u = (unsigned)w3; lw[192] = v.f;
    }
    __syncthreads();

    float a0 = 0.f, a1 = 0.f, a2 = 0.f, a3 = 0.f;
#pragma unroll
    for (int p = 0; p < 8; ++p) {
      f32x4_t h4 = *(const f32x4_t*)(lh + (p << 8) + (lane << 2));  // conflict-free b128
#pragma unroll
      for (int e = 0; e < 4; ++e) {
        float h = h4[e];
        a0 += wreg[0][(p << 2) + e] * h;
        a1 += wreg[1][(p << 2) + e] * h;
        a2 += wreg[2][(p << 2) + e] * h;
        a3 += wreg[3][(p << 2) + e] * h;
      }
    }
#pragma unroll
    for (int s = 32; s >= 1; s >>= 1) {
      a0 += __shfl_xor(a0, s);
      a1 += __shfl_xor(a1, s);
      a2 += __shfl_xor(a2, s);
      a3 += __shfl_xor(a3, s);
    }

    // activations parallelized: lane e<4 does one transcendental (sigma form:
    // tanh(x) = 2*sigma(2x)-1), 4 shfl broadcasts, then uniform c/h on all lanes.
    {
      float pre = ((lane == 0) ? a0 : (lane == 1) ? a1 : (lane == 2) ? a2 : a3) + xv;
      float ps = (lane == 2) ? 2.f * pre : pre;
      float sg = 1.f / (1.f + __expf(-ps));
      float act = (lane == 2) ? 2.f * sg - 1.f : sg;
      float iv = __shfl(act, 0), fv = __shfl(act, 1), gv = __shfl(act, 2),
            ov = __shfl(act, 3);
      c = fv * c + iv * gv;
      float h = ov * fast_tanh(c);
      if (lane == 0 && t + 1 < T) {  // publish: the chip-wide critical path
        union { float f; unsigned u; } hv; hv.f = h * gam;
        size_t slot = (size_t)((t + 1) & (RING - 1)) << 11;
        __hip_atomic_store(&ring[slot | (unsigned)u],
                           (((unsigned long long)(t + 2)) << 32) | hv.u,
                           __ATOMIC_RELAXED, __HIP_MEMORY_SCOPE_AGENT);
      }
      if (lane == 1) hs[(size_t)t * H + u] = h;  // pristine fp32 h for attention
    }
    __syncthreads();  // keep publish ahead of next step's poll flood (see R7)
  }

  // ================= fused attention tail (R18, verified -90us) =================
  epoch_bar(flags, 8);  // all hs[t][*] visible chip-wide

  // attn[t] = dot(hs[t], hs[T-1]); wave handles t == u (256 blocks x 8 waves = 2048)
  {
    const float* rowp = hs + (size_t)u * H;
    const float* hfp = hs + (size_t)(T - 1) * H;
    float s = 0.f;
#pragma unroll
    for (int p = 0; p < 8; ++p) {
      f32x4_t rv = *(const f32x4_t*)(rowp + (p << 8) + (lane << 2));
      f32x4_t fv = *(const f32x4_t*)(hfp + (p << 8) + (lane << 2));
      s += rv[0] * fv[0] + rv[1] * fv[1] + rv[2] * fv[2] + rv[3] * fv[3];
    }
#pragma unroll
    for (int o = 32; o; o >>= 1) s += __shfl_xor(s, o);
    if (lane == 0) attn[u] = s;
  }
  epoch_bar(flags, 9);  // attn[] visible

  if (blockIdx.x >= 64) return;

  // redundant softmax (identical per block) -> weights in lh[]; then 32-row ctx chunk
  {
    const int tid = threadIdx.x;
    f32x4_t av = *(const f32x4_t*)(attn + (tid << 2));
    float m = fmaxf(fmaxf(av[0], av[1]), fmaxf(av[2], av[3]));
#pragma unroll
    for (int o = 32; o; o >>= 1) m = fmaxf(m, __shfl_xor(m, o));
    if (lane == 0) red[wave] = m;
    __syncthreads();
    float M = red[0];
#pragma unroll
    for (int i = 1; i < 8; ++i) M = fmaxf(M, red[i]);
    float e0 = __expf(av[0] - M), e1 = __expf(av[1] - M), e2 = __expf(av[2] - M),
          e3 = __expf(av[3] - M);
    float s = e0 + e1 + e2 + e3;
#pragma unroll
    for (int o = 32; o; o >>= 1) s += __shfl_xor(s, o);
    __syncthreads();  // red[] reuse WAR
    if (lane == 0) red[wave] = s;
    __syncthreads();
    float S = red[0] + red[1] + red[2] + red[3] + red[4] + red[5] + red[6] + red[7];
    float inv = 1.f / S;
    f32x4_t wv = {e0 * inv, e1 * inv, e2 * inv, e3 * inv};
    *(f32x4_t*)(lh + (tid << 2)) = wv;
    __syncthreads();

    // ctx: this block accumulates t-range [32*bid, 32*bid+32) into out[0..2047]
    const int tB = blockIdx.x << 5;
    const float* hp = hs + (size_t)tB * H + (tid << 2);
    float ac0 = 0.f, ac1 = 0.f, ac2 = 0.f, ac3 = 0.f;
#pragma unroll 4
    for (int tt = 0; tt < 32; ++tt) {
      float wt = lh[tB + tt];  // LDS broadcast
      f32x4_t hv = *(const f32x4_t*)hp;
      hp += H;
      ac0 += wt * hv[0]; ac1 += wt * hv[1]; ac2 += wt * hv[2]; ac3 += wt * hv[3];
    }
    int hbase = tid << 2;
    atomicAdd(&out[hbase + 0], ac0);
    atomicAdd(&out[hbase + 1], ac1);
    atomicAdd(&out[hbase + 2], ac2);
    atomicAdd(&out[hbase + 3], ac3);
  }
}

// ---------------- launch ----------------
extern "C" void kernel_launch(void* const* d_in, const int* in_sizes, int n_in,
                              void* d_out, int out_size, void* d_ws, size_t ws_size,
                              hipStream_t stream) {
  const float* x       = (const float*)d_in[0];
  const float* time_   = (const float*)d_in[1];
  const float* W_ih    = (const float*)d_in[2];
  const float* W_hh    = (const float*)d_in[3];
  const float* b_ih    = (const float*)d_in[4];
  const float* b_hh    = (const float*)d_in[5];
  const float* decay_w = (const float*)d_in[6];
  const float* decay_b = (const float*)d_in[7];
  const float* h0      = (const float*)d_in[8];
  const float* c0      = (const float*)d_in[9];

  char* ws = (char*)d_ws;
  float*    xg   = (float*)ws;                          // 64 MB  [T][4H]
  float*    hs   = (float*)(ws + (64u << 20));          // 16 MB  [T][H]
  short*    xb   = (short*)(ws + (80u << 20));          // 4 MB
  short*    wb   = (short*)(ws + (84u << 20));          // 16 MB
  unsigned long long* ring = (unsigned long long*)(ws + (100u << 20)); // 8 MB [RING][H]
  float*    dtp  = (float*)(ws + (108u << 20));
  float*    attn = dtp + T;
  unsigned* flags = (unsigned*)(attn + T);
  float*    outp = (float*)d_out;

  prep_kernel<<<8192, 256, 0, stream>>>(x, W_ih, time_, xb, wb, dtp, flags);

  gemm_xg<<<2048, 256, 0, stream>>>(xb, wb, b_ih, b_hh, xg);

  (void)hipMemsetAsync(d_out, 0, out_size * sizeof(float), stream);

  {
    void* args[] = {&xg, (void*)&W_hh, (void*)&decay_w, (void*)&decay_b,
                    (void*)&h0, (void*)&c0, &dtp, &hs, &ring, &flags, &attn, &outp};
    (void)hipLaunchCooperativeKernel((void*)lstm_rec, dim3(NBLK), dim3(512), args, 0, stream);
  }
}